// Round 10
// baseline (248.876 us; speedup 1.0000x reference)
//
#include <hip/hip_runtime.h>
#include <hip/hip_bf16.h>
#include <math.h>

#define DIM 100
#define BN_EPS 1e-5f
#define AGG_STRIDE 128   // shorts per agg row (100 valid + 28 zero pad) -> 256B
#define SC_BLOCKS 1024
#define HALF_FRAGS (6 * 7 * 64)   // 2688 fragments of 16B = 43008 B per half

using short8v = __attribute__((ext_vector_type(8))) short;
using f32x4v  = __attribute__((ext_vector_type(4))) float;

__device__ __forceinline__ short f2bf(float f) {
    unsigned u = __float_as_uint(f);
    unsigned r = (u + 0x7fffu + ((u >> 16) & 1u)) >> 16;
    return (short)r;
}

// ============ phase 1: row-degree histogram (int4 reads) ============
__global__ void k_hist(const int* __restrict__ ei, int* __restrict__ hist, int E, int NE) {
    int twoE = 2 * E;
    int n4 = twoE >> 2;
    int i4 = blockIdx.x * blockDim.x + threadIdx.x;
    int stride = gridDim.x * blockDim.x;
    for (; i4 < n4; i4 += stride) {
        int4 v = reinterpret_cast<const int4*>(ei)[i4];
        int b = i4 * 4;
        atomicAdd(&hist[((b + 0 < E) ? 0 : NE) + v.x], 1);
        atomicAdd(&hist[((b + 1 < E) ? 0 : NE) + v.y], 1);
        atomicAdd(&hist[((b + 2 < E) ? 0 : NE) + v.z], 1);
        atomicAdd(&hist[((b + 3 < E) ? 0 : NE) + v.w], 1);
    }
    if (blockIdx.x == 0 && threadIdx.x == 0) {
        for (int i = n4 * 4; i < twoE; ++i)
            atomicAdd(&hist[((i < E) ? 0 : NE) + ei[i]], 1);
    }
}

// ============ phase 2a: block-local exclusive scan (+ dinv fused) ============
__global__ void k_scanA(const int* __restrict__ hist, int* __restrict__ base,
                        int* __restrict__ blocksum, float* __restrict__ dinv, int n) {
    __shared__ int lsum[256];
    int tid = threadIdx.x;
    int i0 = blockIdx.x * 1024 + tid * 4;
    int v0 = (i0 + 0 < n) ? hist[i0 + 0] : 0;
    int v1 = (i0 + 1 < n) ? hist[i0 + 1] : 0;
    int v2 = (i0 + 2 < n) ? hist[i0 + 2] : 0;
    int v3 = (i0 + 3 < n) ? hist[i0 + 3] : 0;
    if (i0 + 0 < n) dinv[i0 + 0] = v0 > 0 ? rsqrtf((float)v0) : 0.f;
    if (i0 + 1 < n) dinv[i0 + 1] = v1 > 0 ? rsqrtf((float)v1) : 0.f;
    if (i0 + 2 < n) dinv[i0 + 2] = v2 > 0 ? rsqrtf((float)v2) : 0.f;
    if (i0 + 3 < n) dinv[i0 + 3] = v3 > 0 ? rsqrtf((float)v3) : 0.f;
    int s = v0 + v1 + v2 + v3;
    lsum[tid] = s;
    __syncthreads();
    for (int off = 1; off < 256; off <<= 1) {
        int t = (tid >= off) ? lsum[tid - off] : 0;
        __syncthreads();
        lsum[tid] += t;
        __syncthreads();
    }
    int excl = lsum[tid] - s;
    if (i0 + 0 < n) base[i0 + 0] = excl;
    if (i0 + 1 < n) base[i0 + 1] = excl + v0;
    if (i0 + 2 < n) base[i0 + 2] = excl + v0 + v1;
    if (i0 + 3 < n) base[i0 + 3] = excl + v0 + v1 + v2;
    if (tid == 255) blocksum[blockIdx.x] = lsum[255];
}

// ============ phase 2b: apply block offsets ============
__global__ void k_scanC(int* __restrict__ base, int* __restrict__ cursor,
                        const int* __restrict__ blocksum, int n, int total, int nb) {
    __shared__ int s[256];
    int tid = threadIdx.x;
    int v = (tid < nb) ? blocksum[tid] : 0;
    s[tid] = v;
    __syncthreads();
    for (int off = 1; off < 256; off <<= 1) {
        int t = (tid >= off) ? s[tid - off] : 0;
        __syncthreads();
        s[tid] += t;
        __syncthreads();
    }
    int boff = (blockIdx.x > 0) ? s[blockIdx.x - 1] : 0;
    int i0 = blockIdx.x * 1024 + tid * 4;
#pragma unroll
    for (int j = 0; j < 4; ++j) {
        int i = i0 + j;
        if (i < n) { int w = base[i] + boff; base[i] = w; cursor[i] = w; }
    }
    if (blockIdx.x == 0 && tid == 0) base[n] = total;
}

// ============ phase 3: scatter + W frag prep + rel matmul + xl prep ============
#define WPREP_THREADS (3 * 4 * 7 * 64)
__global__ void k_scatwrel(const int* __restrict__ ei, const int* __restrict__ et,
                           int* __restrict__ cursor, unsigned int* __restrict__ packed,
                           int E, int NE,
                           const float* __restrict__ w_in, const float* __restrict__ w_out,
                           const float* __restrict__ w_loop, short* __restrict__ wfrag,
                           const float* __restrict__ rel, const float* __restrict__ w_rel,
                           float* __restrict__ out2, int nbW, int relTotal4,
                           const float* __restrict__ x, const float* __restrict__ loop_rel,
                           short* __restrict__ xl, int nbR) {
    int tid = threadIdx.x;
    int b = (int)blockIdx.x;
    if (b < SC_BLOCKS) {
        int twoE = 2 * E;
        int n4 = twoE >> 2;
        int i4 = b * 256 + tid;
        int stride = SC_BLOCKS * 256;
        for (; i4 < n4; i4 += stride) {
            int4 r4 = reinterpret_cast<const int4*>(ei)[i4];
            int4 c4 = *reinterpret_cast<const int4*>(ei + twoE + i4 * 4);
            int4 t4 = reinterpret_cast<const int4*>(et)[i4];
            int bidx = i4 * 4;
#define SCAT(comp, o) { int slot = ((bidx + o < E) ? 0 : NE) + r4.comp;                  \
                        int pos = atomicAdd(&cursor[slot], 1);                           \
                        packed[pos] = (unsigned int)c4.comp | ((unsigned int)t4.comp << 17); }
        SCAT(x, 0) SCAT(y, 1) SCAT(z, 2) SCAT(w, 3)
#undef SCAT
        }
        if (b == 0 && tid == 0) {
            for (int i = n4 * 4; i < twoE; ++i) {
                int slot = ((i < E) ? 0 : NE) + ei[i];
                int pos = atomicAdd(&cursor[slot], 1);
                packed[pos] = (unsigned int)ei[twoE + i] | ((unsigned int)et[i] << 17);
            }
        }
    } else if (b < SC_BLOCKS + nbW) {
        int g = (b - SC_BLOCKS) * 256 + tid;
        if (g >= WPREP_THREADS) return;
        int lane = g & 63;
        int rest = g >> 6;
        int nt = rest % 7;
        int ks = (rest / 7) % 4;
        int src = rest / 28;
        const float* W = (src == 0) ? w_in : (src == 1) ? w_out : w_loop;
        int col = nt * 16 + (lane & 15);
        short8v frag;
#pragma unroll
        for (int j = 0; j < 8; ++j) {
            int k = ks * 32 + ((lane >> 4) << 3) + j;
            float v = (k < DIM && col < DIM) ? W[k * DIM + col] : 0.f;
            frag[j] = f2bf(v);
        }
        reinterpret_cast<short8v*>(wfrag)[g] = frag;
    } else if (b < SC_BLOCKS + nbW + nbR) {
        int i = (b - SC_BLOCKS - nbW) * 256 + tid;
        if (i >= relTotal4) return;
        int r = i / 25;
        int d = (i - r * 25) * 4;
        const float* a = rel + r * DIM;
        float4 acc = make_float4(0.f, 0.f, 0.f, 0.f);
#pragma unroll 4
        for (int k = 0; k < DIM; ++k) {
            float av = a[k];
            float4 w = *reinterpret_cast<const float4*>(w_rel + k * DIM + d);
            acc.x += av * w.x; acc.y += av * w.y; acc.z += av * w.z; acc.w += av * w.w;
        }
        *reinterpret_cast<float4*>(out2 + r * DIM + d) = acc;
    } else {
        if (!xl) return;
        int i = (b - SC_BLOCKS - nbW - nbR) * 256 + tid;
        if (i >= NE * 25) return;
        int r = i / 25;
        int c4 = (i - r * 25) * 4;
        float4 xv = *reinterpret_cast<const float4*>(x + (size_t)r * DIM + c4);
        float4 lv = *reinterpret_cast<const float4*>(loop_rel + c4);
        short4 sv;
        sv.x = f2bf(xv.x * lv.x); sv.y = f2bf(xv.y * lv.y);
        sv.z = f2bf(xv.z * lv.z); sv.w = f2bf(xv.w * lv.w);
        short* dst = xl + (size_t)r * AGG_STRIDE;
        *reinterpret_cast<short4*>(dst + c4) = sv;
        if (c4 == 96) {
            short4 z; z.x = 0; z.y = 0; z.z = 0; z.w = 0;
#pragma unroll
            for (int p = 100; p < 128; p += 4)
                *reinterpret_cast<short4*>(dst + p) = z;
        }
    }
}

// ============ phase 4: gather-aggregate, one CSR row per wave, 6 edges in flight ===========
__global__ __launch_bounds__(256) void k_agg2(
    const unsigned int* __restrict__ packed, const int* __restrict__ base,
    const float* __restrict__ x, const float* __restrict__ rel,
    const float* __restrict__ dinv,
    short* __restrict__ aggbf, int NE) {
    int tid = threadIdx.x;
    int row = blockIdx.x * 4 + (tid >> 6);
    if (row >= 2 * NE) return;
    int lane = tid & 63;
    int sub = lane >> 5;
    int slot = lane & 31;
    int d = (slot < 25) ? slot * 4 : 96;
    int dbase = (row < NE) ? 0 : NE;
    float dr = dinv[row];
    int s = base[row], e = base[row + 1];

    float4 acc0 = make_float4(0.f, 0.f, 0.f, 0.f);
    float4 acc1 = make_float4(0.f, 0.f, 0.f, 0.f);
    float4 acc2 = make_float4(0.f, 0.f, 0.f, 0.f);
    int j = s + sub;
    for (; j + 4 < e; j += 6) {
        unsigned int p0 = packed[j];
        unsigned int p1 = packed[j + 2];
        unsigned int p2 = packed[j + 4];
        int c0 = (int)(p0 & 0x1FFFFu), t0 = (int)(p0 >> 17);
        int c1 = (int)(p1 & 0x1FFFFu), t1 = (int)(p1 >> 17);
        int c2 = (int)(p2 & 0x1FFFFu), t2 = (int)(p2 >> 17);
        float n0 = dr * dinv[dbase + c0];
        float n1 = dr * dinv[dbase + c1];
        float n2 = dr * dinv[dbase + c2];
        float4 xv0 = *reinterpret_cast<const float4*>(x + c0 * DIM + d);
        float4 rv0 = *reinterpret_cast<const float4*>(rel + t0 * DIM + d);
        float4 xv1 = *reinterpret_cast<const float4*>(x + c1 * DIM + d);
        float4 rv1 = *reinterpret_cast<const float4*>(rel + t1 * DIM + d);
        float4 xv2 = *reinterpret_cast<const float4*>(x + c2 * DIM + d);
        float4 rv2 = *reinterpret_cast<const float4*>(rel + t2 * DIM + d);
        acc0.x += xv0.x * rv0.x * n0; acc0.y += xv0.y * rv0.y * n0;
        acc0.z += xv0.z * rv0.z * n0; acc0.w += xv0.w * rv0.w * n0;
        acc1.x += xv1.x * rv1.x * n1; acc1.y += xv1.y * rv1.y * n1;
        acc1.z += xv1.z * rv1.z * n1; acc1.w += xv1.w * rv1.w * n1;
        acc2.x += xv2.x * rv2.x * n2; acc2.y += xv2.y * rv2.y * n2;
        acc2.z += xv2.z * rv2.z * n2; acc2.w += xv2.w * rv2.w * n2;
    }
    for (; j < e; j += 2) {
        unsigned int p0 = packed[j];
        int c0 = (int)(p0 & 0x1FFFFu), t0 = (int)(p0 >> 17);
        float n0 = dr * dinv[dbase + c0];
        float4 xv0 = *reinterpret_cast<const float4*>(x + c0 * DIM + d);
        float4 rv0 = *reinterpret_cast<const float4*>(rel + t0 * DIM + d);
        acc0.x += xv0.x * rv0.x * n0; acc0.y += xv0.y * rv0.y * n0;
        acc0.z += xv0.z * rv0.z * n0; acc0.w += xv0.w * rv0.w * n0;
    }
    acc0.x += acc1.x + acc2.x; acc0.y += acc1.y + acc2.y;
    acc0.z += acc1.z + acc2.z; acc0.w += acc1.w + acc2.w;
    acc0.x += __shfl_down(acc0.x, 32, 64);
    acc0.y += __shfl_down(acc0.y, 32, 64);
    acc0.z += __shfl_down(acc0.z, 32, 64);
    acc0.w += __shfl_down(acc0.w, 32, 64);
    if (sub == 0) {
        short4 sv;
        if (slot < 25) {
            sv.x = f2bf(acc0.x); sv.y = f2bf(acc0.y);
            sv.z = f2bf(acc0.z); sv.w = f2bf(acc0.w);
        } else {
            sv.x = 0; sv.y = 0; sv.z = 0; sv.w = 0;
        }
        *reinterpret_cast<short4*>(aggbf + (size_t)row * AGG_STRIDE + slot * 4) = sv;
    }
}

// ============ MFMA GEMM + fused stats + grid barrier + BN + tanh ============
// 196 blocks of 512 threads, LDS 44KB -> all blocks co-resident (<=256 CUs at >=1/CU),
// so a device-scope atomic barrier is safe (counter zeroed by host memset each replay).
__global__ __launch_bounds__(512) void k_gemm_bn(
    const short* __restrict__ abuf,    // [3NE][128] bf16 (in|out|x.*loop) if hasXL, else [2NE][128]
    const float* __restrict__ x, const float* __restrict__ loop_rel, int hasXL,
    const short* __restrict__ wfrag, float* __restrict__ out,
    float* __restrict__ colsum, float* __restrict__ colsumsq, int* ctr,
    const float* __restrict__ gamma, const float* __restrict__ beta, int NE) {
    __shared__ short8v wlds[HALF_FRAGS];
    __shared__ float cs[112], cq[112];
    int tid = threadIdx.x;
    if (tid < 112) { cs[tid] = 0.f; cq[tid] = 0.f; }

    int wv = tid >> 6;
    int lane = tid & 63;
    int kg = lane >> 4;
    int cbase = lane & 15;
    int pair = blockIdx.x * 8 + wv;
    bool t0v = (pair * 32 < NE);
    int r0 = pair * 32 + cbase;
    int r1 = r0 + 16;
    int rA0 = (r0 < NE) ? r0 : (NE - 1);
    int rA1 = (r1 < NE) ? r1 : (NE - 1);
    const float* Arow0 = x + (size_t)rA0 * DIM;
    const float* Arow1 = x + (size_t)rA1 * DIM;
    const short8v* wfragv = reinterpret_cast<const short8v*>(wfrag);

    f32x4v acc0[7], acc1[7];
#pragma unroll
    for (int nt = 0; nt < 7; ++nt) {
        acc0[nt] = (f32x4v){0.f, 0.f, 0.f, 0.f};
        acc1[nt] = (f32x4v){0.f, 0.f, 0.f, 0.f};
    }

#pragma unroll
    for (int h = 0; h < 2; ++h) {
        if (h > 0) __syncthreads();
        for (int i = tid; i < HALF_FRAGS; i += 512)
            wlds[i] = wfragv[h * HALF_FRAGS + i];
        __syncthreads();
        if (t0v) {
#pragma unroll
            for (int kk = 0; kk < 6; ++kk) {
                int kstep = h * 6 + kk;
                short8v af0, af1;
                if (hasXL || kstep < 8) {
                    size_t off = (size_t)(kstep >> 2) * NE * AGG_STRIDE;
                    int ko = (kstep & 3) * 32 + kg * 8;
                    af0 = *reinterpret_cast<const short8v*>(abuf + off + (size_t)rA0 * AGG_STRIDE + ko);
                    af1 = *reinterpret_cast<const short8v*>(abuf + off + (size_t)rA1 * AGG_STRIDE + ko);
                } else {
                    int ks = kstep - 8;
                    short8v a0 = (short8v){0,0,0,0,0,0,0,0};
                    short8v a1 = (short8v){0,0,0,0,0,0,0,0};
                    if (ks < 3) {
                        int k0 = ks * 32 + kg * 8;
                        float4 l0 = *reinterpret_cast<const float4*>(loop_rel + k0);
                        float4 l1 = *reinterpret_cast<const float4*>(loop_rel + k0 + 4);
                        float4 lo0 = *reinterpret_cast<const float4*>(Arow0 + k0);
                        float4 hi0 = *reinterpret_cast<const float4*>(Arow0 + k0 + 4);
                        float4 lo1 = *reinterpret_cast<const float4*>(Arow1 + k0);
                        float4 hi1 = *reinterpret_cast<const float4*>(Arow1 + k0 + 4);
                        a0[0]=f2bf(lo0.x*l0.x); a0[1]=f2bf(lo0.y*l0.y); a0[2]=f2bf(lo0.z*l0.z); a0[3]=f2bf(lo0.w*l0.w);
                        a0[4]=f2bf(hi0.x*l1.x); a0[5]=f2bf(hi0.y*l1.y); a0[6]=f2bf(hi0.z*l1.z); a0[7]=f2bf(hi0.w*l1.w);
                        a1[0]=f2bf(lo1.x*l0.x); a1[1]=f2bf(lo1.y*l0.y); a1[2]=f2bf(lo1.z*l0.z); a1[3]=f2bf(lo1.w*l0.w);
                        a1[4]=f2bf(hi1.x*l1.x); a1[5]=f2bf(hi1.y*l1.y); a1[6]=f2bf(hi1.z*l1.z); a1[7]=f2bf(hi1.w*l1.w);
                    } else if (kg == 0) {
                        float4 l0 = *reinterpret_cast<const float4*>(loop_rel + 96);
                        float4 lo0 = *reinterpret_cast<const float4*>(Arow0 + 96);
                        float4 lo1 = *reinterpret_cast<const float4*>(Arow1 + 96);
                        a0[0]=f2bf(lo0.x*l0.x); a0[1]=f2bf(lo0.y*l0.y); a0[2]=f2bf(lo0.z*l0.z); a0[3]=f2bf(lo0.w*l0.w);
                        a1[0]=f2bf(lo1.x*l0.x); a1[1]=f2bf(lo1.y*l0.y); a1[2]=f2bf(lo1.z*l0.z); a1[3]=f2bf(lo1.w*l0.w);
                    }
                    af0 = a0; af1 = a1;
                }
#pragma unroll
                for (int nt = 0; nt < 7; ++nt) {
                    short8v bf = wlds[(kk * 7 + nt) * 64 + lane];
                    acc0[nt] = __builtin_amdgcn_mfma_f32_16x16x32_bf16(af0, bf, acc0[nt], 0, 0, 0);
                    acc1[nt] = __builtin_amdgcn_mfma_f32_16x16x32_bf16(af1, bf, acc1[nt], 0, 0, 0);
                }
            }
        }
    }

    // ---- per-block column stats (values stay in registers) ----
    if (t0v) {
#pragma unroll
        for (int nt = 0; nt < 7; ++nt) {
            int col = nt * 16 + cbase;
            if (col < DIM) {
                float ps = 0.f, pq = 0.f;
#pragma unroll
                for (int r = 0; r < 4; ++r) {
                    int orow = pair * 32 + kg * 4 + r;
                    if (orow < NE) { float v = acc0[nt][r]; ps += v; pq += v * v; }
                }
#pragma unroll
                for (int r = 0; r < 4; ++r) {
                    int orow = pair * 32 + 16 + kg * 4 + r;
                    if (orow < NE) { float v = acc1[nt][r]; ps += v; pq += v * v; }
                }
                atomicAdd(&cs[col], ps);
                atomicAdd(&cq[col], pq);
            }
        }
    }
    __syncthreads();
    if (tid < DIM) {
        atomicAdd(&colsum[tid], cs[tid]);
        atomicAdd(&colsumsq[tid], cq[tid]);
    }

    // ---- grid barrier (all blocks co-resident) ----
    __syncthreads();
    if (tid == 0) {
        __threadfence();
        atomicAdd(ctr, 1);
        while (atomicAdd(ctr, 0) < (int)gridDim.x) { __builtin_amdgcn_s_sleep(1); }
    }
    __syncthreads();
    __threadfence();   // invalidate L1 so colsum reads see L2 values

    // ---- BN + tanh from registers, single store ----
    if (t0v) {
        float invN = 1.0f / (float)NE;
#pragma unroll
        for (int nt = 0; nt < 7; ++nt) {
            int col = nt * 16 + cbase;
            if (col < DIM) {
                float mu = colsum[col] * invN;
                float var = colsumsq[col] * invN - mu * mu;
                if (var < 0.f) var = 0.f;
                float S = rsqrtf(var * (1.0f / 9.0f) + BN_EPS) * (1.0f / 3.0f) * gamma[col];
                float T = beta[col] - mu * S;
#pragma unroll
                for (int r = 0; r < 4; ++r) {
                    int orow = pair * 32 + kg * 4 + r;
                    if (orow < NE)
                        out[(size_t)orow * DIM + col] = tanhf(acc0[nt][r] * S + T);
                }
#pragma unroll
                for (int r = 0; r < 4; ++r) {
                    int orow = pair * 32 + 16 + kg * 4 + r;
                    if (orow < NE)
                        out[(size_t)orow * DIM + col] = tanhf(acc1[nt][r] * S + T);
                }
            }
        }
    }
}

extern "C" void kernel_launch(void* const* d_in, const int* in_sizes, int n_in,
                              void* d_out, int out_size, void* d_ws, size_t ws_size,
                              hipStream_t stream) {
    const float* x        = (const float*)d_in[0];
    const int*   ei       = (const int*)d_in[1];
    const int*   et       = (const int*)d_in[2];
    const float* rel      = (const float*)d_in[3];
    const float* w_in     = (const float*)d_in[4];
    const float* w_out    = (const float*)d_in[5];
    const float* w_loop   = (const float*)d_in[6];
    const float* w_rel    = (const float*)d_in[7];
    const float* loop_rel = (const float*)d_in[8];
    const float* gamma    = (const float*)d_in[10];
    const float* beta     = (const float*)d_in[11];

    const int NE = in_sizes[0] / DIM;     // 50000
    const int E  = in_sizes[2] / 2;       // 500000

    float* out  = (float*)d_out;
    float* out2 = out + (size_t)NE * DIM;
    const int relRows = in_sizes[3] / DIM;

    const int B = 256;
    const size_t twoNE = 2 * (size_t)NE;
    const int n = (int)twoNE;
    const int nb = (n + 1023) / 1024;
    const int WFRAG_SHORTS = 3 * 4 * 7 * 64 * 8;
    const int WFRAG_INTS = WFRAG_SHORTS / 2;

    // ws layout (ints):
    // hist[2NE] | colsum[128] colsumsq[128] | blocksum[128]
    // | dinv[2NE] | base[2NE+16] | cursor[2NE] | wfrag[21504] | packed[2E] | abuf[(2|3)NE*64]
    int* wsI = (int*)d_ws;
    int*   hist     = wsI;
    float* colsum   = (float*)(hist + twoNE);
    float* colsumsq = colsum + 128;
    int*   ctr      = (int*)(colsum + 120);   // inside zeroed region, cols used only 0..99
    int*   blocksum = (int*)(colsumsq + 128);
    float* dinv     = (float*)(blocksum + 128);
    int*   base     = (int*)(dinv + twoNE);
    int*   cursor   = base + twoNE + 16;
    short* wfrag    = (short*)(cursor + twoNE);
    unsigned int* packed = (unsigned int*)(cursor + twoNE + WFRAG_INTS);
    short* abuf     = (short*)(packed + 2 * (size_t)E);

    const size_t fixedInts = twoNE + 256 + 128 + twoNE + (twoNE + 16) + twoNE
                             + WFRAG_INTS + 2 * (size_t)E;
    const size_t needXL = (fixedInts + 3 * (size_t)NE * (AGG_STRIDE / 2)) * 4;
    const int hasXL = (ws_size >= needXL) ? 1 : 0;
    short* xl = hasXL ? (abuf + twoNE * AGG_STRIDE) : nullptr;

    const int relTotal4 = relRows * (DIM / 4);
    const int nbW = (WPREP_THREADS + 255) / 256;
    const int nbR = (relTotal4 + 255) / 256;
    const int nbX = hasXL ? ((NE * 25 + 255) / 256) : 0;

    hipMemsetAsync(hist, 0, (twoNE + 256) * 4, stream);

    k_hist<<<1024, B, 0, stream>>>(ei, hist, E, NE);
    k_scanA<<<nb, B, 0, stream>>>(hist, base, blocksum, dinv, n);
    k_scanC<<<nb, B, 0, stream>>>(base, cursor, blocksum, n, 2 * E, nb);
    k_scatwrel<<<SC_BLOCKS + nbW + nbR + nbX, B, 0, stream>>>(
        ei, et, cursor, packed, E, NE, w_in, w_out, w_loop, wfrag,
        rel, w_rel, out2, nbW, relTotal4, x, loop_rel, xl, nbR);
    k_agg2<<<(n + 3) / 4, B, 0, stream>>>(packed, base, x, rel, dinv, abuf, NE);

    int nPairs = (NE + 31) / 32;
    int gBlocks = (nPairs + 7) / 8;
    k_gemm_bn<<<gBlocks, 512, 0, stream>>>(abuf, x, loop_rel, hasXL, wfrag, out,
                                           colsum, colsumsq, ctr, gamma, beta, NE);
}

// Round 11
// 221.131 us; speedup vs baseline: 1.1255x; 1.1255x over previous
//
#include <hip/hip_runtime.h>
#include <hip/hip_bf16.h>
#include <math.h>

#define DIM 100
#define BN_EPS 1e-5f
#define AGG_STRIDE 128   // shorts per agg row (100 valid + 28 zero pad) -> 256B
#define SC_BLOCKS 1024
#define HALF_FRAGS (6 * 7 * 64)   // 2688 fragments of 16B = 43008 B per half

using short8v = __attribute__((ext_vector_type(8))) short;
using f32x4v  = __attribute__((ext_vector_type(4))) float;

__device__ __forceinline__ short f2bf(float f) {
    unsigned u = __float_as_uint(f);
    unsigned r = (u + 0x7fffu + ((u >> 16) & 1u)) >> 16;
    return (short)r;
}

// ============ phase 1: row-degree histogram (int4 reads) ============
__global__ void k_hist(const int* __restrict__ ei, int* __restrict__ hist, int E, int NE) {
    int twoE = 2 * E;
    int n4 = twoE >> 2;
    int i4 = blockIdx.x * blockDim.x + threadIdx.x;
    int stride = gridDim.x * blockDim.x;
    for (; i4 < n4; i4 += stride) {
        int4 v = reinterpret_cast<const int4*>(ei)[i4];
        int b = i4 * 4;
        atomicAdd(&hist[((b + 0 < E) ? 0 : NE) + v.x], 1);
        atomicAdd(&hist[((b + 1 < E) ? 0 : NE) + v.y], 1);
        atomicAdd(&hist[((b + 2 < E) ? 0 : NE) + v.z], 1);
        atomicAdd(&hist[((b + 3 < E) ? 0 : NE) + v.w], 1);
    }
    if (blockIdx.x == 0 && threadIdx.x == 0) {
        for (int i = n4 * 4; i < twoE; ++i)
            atomicAdd(&hist[((i < E) ? 0 : NE) + ei[i]], 1);
    }
}

// ============ phase 2a: block-local exclusive scan (+ dinv fused) ============
__global__ void k_scanA(const int* __restrict__ hist, int* __restrict__ base,
                        int* __restrict__ blocksum, float* __restrict__ dinv, int n) {
    __shared__ int lsum[256];
    int tid = threadIdx.x;
    int i0 = blockIdx.x * 1024 + tid * 4;
    int v0 = (i0 + 0 < n) ? hist[i0 + 0] : 0;
    int v1 = (i0 + 1 < n) ? hist[i0 + 1] : 0;
    int v2 = (i0 + 2 < n) ? hist[i0 + 2] : 0;
    int v3 = (i0 + 3 < n) ? hist[i0 + 3] : 0;
    if (i0 + 0 < n) dinv[i0 + 0] = v0 > 0 ? rsqrtf((float)v0) : 0.f;
    if (i0 + 1 < n) dinv[i0 + 1] = v1 > 0 ? rsqrtf((float)v1) : 0.f;
    if (i0 + 2 < n) dinv[i0 + 2] = v2 > 0 ? rsqrtf((float)v2) : 0.f;
    if (i0 + 3 < n) dinv[i0 + 3] = v3 > 0 ? rsqrtf((float)v3) : 0.f;
    int s = v0 + v1 + v2 + v3;
    lsum[tid] = s;
    __syncthreads();
    for (int off = 1; off < 256; off <<= 1) {
        int t = (tid >= off) ? lsum[tid - off] : 0;
        __syncthreads();
        lsum[tid] += t;
        __syncthreads();
    }
    int excl = lsum[tid] - s;
    if (i0 + 0 < n) base[i0 + 0] = excl;
    if (i0 + 1 < n) base[i0 + 1] = excl + v0;
    if (i0 + 2 < n) base[i0 + 2] = excl + v0 + v1;
    if (i0 + 3 < n) base[i0 + 3] = excl + v0 + v1 + v2;
    if (tid == 255) blocksum[blockIdx.x] = lsum[255];
}

// ============ phase 2b: apply block offsets ============
__global__ void k_scanC(int* __restrict__ base, int* __restrict__ cursor,
                        const int* __restrict__ blocksum, int n, int total, int nb) {
    __shared__ int s[256];
    int tid = threadIdx.x;
    int v = (tid < nb) ? blocksum[tid] : 0;
    s[tid] = v;
    __syncthreads();
    for (int off = 1; off < 256; off <<= 1) {
        int t = (tid >= off) ? s[tid - off] : 0;
        __syncthreads();
        s[tid] += t;
        __syncthreads();
    }
    int boff = (blockIdx.x > 0) ? s[blockIdx.x - 1] : 0;
    int i0 = blockIdx.x * 1024 + tid * 4;
#pragma unroll
    for (int j = 0; j < 4; ++j) {
        int i = i0 + j;
        if (i < n) { int w = base[i] + boff; base[i] = w; cursor[i] = w; }
    }
    if (blockIdx.x == 0 && tid == 0) base[n] = total;
}

// ============ phase 3: scatter + W frag prep + rel matmul + xl prep ============
#define WPREP_THREADS (3 * 4 * 7 * 64)
__global__ void k_scatwrel(const int* __restrict__ ei, const int* __restrict__ et,
                           int* __restrict__ cursor, unsigned int* __restrict__ packed,
                           int E, int NE,
                           const float* __restrict__ w_in, const float* __restrict__ w_out,
                           const float* __restrict__ w_loop, short* __restrict__ wfrag,
                           const float* __restrict__ rel, const float* __restrict__ w_rel,
                           float* __restrict__ out2, int nbW, int relTotal4,
                           const float* __restrict__ x, const float* __restrict__ loop_rel,
                           short* __restrict__ xl, int nbR) {
    int tid = threadIdx.x;
    int b = (int)blockIdx.x;
    if (b < SC_BLOCKS) {
        int twoE = 2 * E;
        int n4 = twoE >> 2;
        int i4 = b * 256 + tid;
        int stride = SC_BLOCKS * 256;
        for (; i4 < n4; i4 += stride) {
            int4 r4 = reinterpret_cast<const int4*>(ei)[i4];
            int4 c4 = *reinterpret_cast<const int4*>(ei + twoE + i4 * 4);
            int4 t4 = reinterpret_cast<const int4*>(et)[i4];
            int bidx = i4 * 4;
#define SCAT(comp, o) { int slot = ((bidx + o < E) ? 0 : NE) + r4.comp;                  \
                        int pos = atomicAdd(&cursor[slot], 1);                           \
                        packed[pos] = (unsigned int)c4.comp | ((unsigned int)t4.comp << 17); }
        SCAT(x, 0) SCAT(y, 1) SCAT(z, 2) SCAT(w, 3)
#undef SCAT
        }
        if (b == 0 && tid == 0) {
            for (int i = n4 * 4; i < twoE; ++i) {
                int slot = ((i < E) ? 0 : NE) + ei[i];
                int pos = atomicAdd(&cursor[slot], 1);
                packed[pos] = (unsigned int)ei[twoE + i] | ((unsigned int)et[i] << 17);
            }
        }
    } else if (b < SC_BLOCKS + nbW) {
        int g = (b - SC_BLOCKS) * 256 + tid;
        if (g >= WPREP_THREADS) return;
        int lane = g & 63;
        int rest = g >> 6;
        int nt = rest % 7;
        int ks = (rest / 7) % 4;
        int src = rest / 28;
        const float* W = (src == 0) ? w_in : (src == 1) ? w_out : w_loop;
        int col = nt * 16 + (lane & 15);
        short8v frag;
#pragma unroll
        for (int j = 0; j < 8; ++j) {
            int k = ks * 32 + ((lane >> 4) << 3) + j;
            float v = (k < DIM && col < DIM) ? W[k * DIM + col] : 0.f;
            frag[j] = f2bf(v);
        }
        reinterpret_cast<short8v*>(wfrag)[g] = frag;
    } else if (b < SC_BLOCKS + nbW + nbR) {
        int i = (b - SC_BLOCKS - nbW) * 256 + tid;
        if (i >= relTotal4) return;
        int r = i / 25;
        int d = (i - r * 25) * 4;
        const float* a = rel + r * DIM;
        float4 acc = make_float4(0.f, 0.f, 0.f, 0.f);
#pragma unroll 4
        for (int k = 0; k < DIM; ++k) {
            float av = a[k];
            float4 w = *reinterpret_cast<const float4*>(w_rel + k * DIM + d);
            acc.x += av * w.x; acc.y += av * w.y; acc.z += av * w.z; acc.w += av * w.w;
        }
        *reinterpret_cast<float4*>(out2 + r * DIM + d) = acc;
    } else {
        if (!xl) return;
        int i = (b - SC_BLOCKS - nbW - nbR) * 256 + tid;
        if (i >= NE * 25) return;
        int r = i / 25;
        int c4 = (i - r * 25) * 4;
        float4 xv = *reinterpret_cast<const float4*>(x + (size_t)r * DIM + c4);
        float4 lv = *reinterpret_cast<const float4*>(loop_rel + c4);
        short4 sv;
        sv.x = f2bf(xv.x * lv.x); sv.y = f2bf(xv.y * lv.y);
        sv.z = f2bf(xv.z * lv.z); sv.w = f2bf(xv.w * lv.w);
        short* dst = xl + (size_t)r * AGG_STRIDE;
        *reinterpret_cast<short4*>(dst + c4) = sv;
        if (c4 == 96) {
            short4 z; z.x = 0; z.y = 0; z.z = 0; z.w = 0;
#pragma unroll
            for (int p = 100; p < 128; p += 4)
                *reinterpret_cast<short4*>(dst + p) = z;
        }
    }
}

// ============ phase 4: gather-aggregate, one CSR row per wave, 6 edges in flight ===========
__global__ __launch_bounds__(256) void k_agg2(
    const unsigned int* __restrict__ packed, const int* __restrict__ base,
    const float* __restrict__ x, const float* __restrict__ rel,
    const float* __restrict__ dinv,
    short* __restrict__ aggbf, int NE) {
    int tid = threadIdx.x;
    int row = blockIdx.x * 4 + (tid >> 6);
    if (row >= 2 * NE) return;
    int lane = tid & 63;
    int sub = lane >> 5;
    int slot = lane & 31;
    int d = (slot < 25) ? slot * 4 : 96;
    int dbase = (row < NE) ? 0 : NE;
    float dr = dinv[row];
    int s = base[row], e = base[row + 1];

    float4 acc0 = make_float4(0.f, 0.f, 0.f, 0.f);
    float4 acc1 = make_float4(0.f, 0.f, 0.f, 0.f);
    float4 acc2 = make_float4(0.f, 0.f, 0.f, 0.f);
    int j = s + sub;
    for (; j + 4 < e; j += 6) {
        unsigned int p0 = packed[j];
        unsigned int p1 = packed[j + 2];
        unsigned int p2 = packed[j + 4];
        int c0 = (int)(p0 & 0x1FFFFu), t0 = (int)(p0 >> 17);
        int c1 = (int)(p1 & 0x1FFFFu), t1 = (int)(p1 >> 17);
        int c2 = (int)(p2 & 0x1FFFFu), t2 = (int)(p2 >> 17);
        float n0 = dr * dinv[dbase + c0];
        float n1 = dr * dinv[dbase + c1];
        float n2 = dr * dinv[dbase + c2];
        float4 xv0 = *reinterpret_cast<const float4*>(x + c0 * DIM + d);
        float4 rv0 = *reinterpret_cast<const float4*>(rel + t0 * DIM + d);
        float4 xv1 = *reinterpret_cast<const float4*>(x + c1 * DIM + d);
        float4 rv1 = *reinterpret_cast<const float4*>(rel + t1 * DIM + d);
        float4 xv2 = *reinterpret_cast<const float4*>(x + c2 * DIM + d);
        float4 rv2 = *reinterpret_cast<const float4*>(rel + t2 * DIM + d);
        acc0.x += xv0.x * rv0.x * n0; acc0.y += xv0.y * rv0.y * n0;
        acc0.z += xv0.z * rv0.z * n0; acc0.w += xv0.w * rv0.w * n0;
        acc1.x += xv1.x * rv1.x * n1; acc1.y += xv1.y * rv1.y * n1;
        acc1.z += xv1.z * rv1.z * n1; acc1.w += xv1.w * rv1.w * n1;
        acc2.x += xv2.x * rv2.x * n2; acc2.y += xv2.y * rv2.y * n2;
        acc2.z += xv2.z * rv2.z * n2; acc2.w += xv2.w * rv2.w * n2;
    }
    for (; j < e; j += 2) {
        unsigned int p0 = packed[j];
        int c0 = (int)(p0 & 0x1FFFFu), t0 = (int)(p0 >> 17);
        float n0 = dr * dinv[dbase + c0];
        float4 xv0 = *reinterpret_cast<const float4*>(x + c0 * DIM + d);
        float4 rv0 = *reinterpret_cast<const float4*>(rel + t0 * DIM + d);
        acc0.x += xv0.x * rv0.x * n0; acc0.y += xv0.y * rv0.y * n0;
        acc0.z += xv0.z * rv0.z * n0; acc0.w += xv0.w * rv0.w * n0;
    }
    acc0.x += acc1.x + acc2.x; acc0.y += acc1.y + acc2.y;
    acc0.z += acc1.z + acc2.z; acc0.w += acc1.w + acc2.w;
    acc0.x += __shfl_down(acc0.x, 32, 64);
    acc0.y += __shfl_down(acc0.y, 32, 64);
    acc0.z += __shfl_down(acc0.z, 32, 64);
    acc0.w += __shfl_down(acc0.w, 32, 64);
    if (sub == 0) {
        short4 sv;
        if (slot < 25) {
            sv.x = f2bf(acc0.x); sv.y = f2bf(acc0.y);
            sv.z = f2bf(acc0.z); sv.w = f2bf(acc0.w);
        } else {
            sv.x = 0; sv.y = 0; sv.z = 0; sv.w = 0;
        }
        *reinterpret_cast<short4*>(aggbf + (size_t)row * AGG_STRIDE + slot * 4) = sv;
    }
}

// ============ MFMA GEMM: 8 waves/block, 2 row-tiles/wave, A-frags register-prefetched ============
__global__ __launch_bounds__(512) void k_gemm_mfma(
    const short* __restrict__ abuf,    // [3NE][128] bf16 (in|out|x.*loop) if hasXL, else [2NE][128]
    const float* __restrict__ x, const float* __restrict__ loop_rel, int hasXL,
    const short* __restrict__ wfrag, float* __restrict__ out,
    float* __restrict__ colsum, float* __restrict__ colsumsq, int NE) {
    __shared__ short8v wlds[HALF_FRAGS];
    __shared__ float cs[112], cq[112];
    int tid = threadIdx.x;
    if (tid < 112) { cs[tid] = 0.f; cq[tid] = 0.f; }

    int wv = tid >> 6;
    int lane = tid & 63;
    int kg = lane >> 4;
    int cbase = lane & 15;
    int pair = blockIdx.x * 8 + wv;
    bool t0v = (pair * 32 < NE);
    int r0 = pair * 32 + cbase;
    int r1 = r0 + 16;
    int rA0 = (r0 < NE) ? r0 : (NE - 1);
    int rA1 = (r1 < NE) ? r1 : (NE - 1);
    const float* Arow0 = x + (size_t)rA0 * DIM;
    const float* Arow1 = x + (size_t)rA1 * DIM;
    const short8v* wfragv = reinterpret_cast<const short8v*>(wfrag);
    const short* a0base = abuf + (size_t)rA0 * AGG_STRIDE + kg * 8;
    const short* a1base = abuf + (size_t)rA1 * AGG_STRIDE + kg * 8;
    const size_t srcOff = (size_t)NE * AGG_STRIDE;

    f32x4v acc0[7], acc1[7];
#pragma unroll
    for (int nt = 0; nt < 7; ++nt) {
        acc0[nt] = (f32x4v){0.f, 0.f, 0.f, 0.f};
        acc1[nt] = (f32x4v){0.f, 0.f, 0.f, 0.f};
    }

#pragma unroll
    for (int h = 0; h < 2; ++h) {
        if (h > 0) __syncthreads();
        // ---- issue all 12 independent A-frag loads for this half FIRST (ILP burst) ----
        short8v afr0[6], afr1[6];
        if (t0v) {
            if (hasXL) {
#pragma unroll
                for (int kk = 0; kk < 6; ++kk) {
                    int kstep = h * 6 + kk;
                    size_t off = (size_t)(kstep >> 2) * srcOff + (kstep & 3) * 32;
                    afr0[kk] = *reinterpret_cast<const short8v*>(a0base + off);
                    afr1[kk] = *reinterpret_cast<const short8v*>(a1base + off);
                }
            } else {
#pragma unroll
                for (int kk = 0; kk < 6; ++kk) {
                    int kstep = h * 6 + kk;
                    short8v a0 = (short8v){0,0,0,0,0,0,0,0};
                    short8v a1 = (short8v){0,0,0,0,0,0,0,0};
                    if (kstep < 8) {
                        size_t off = (size_t)(kstep >> 2) * srcOff + (kstep & 3) * 32;
                        a0 = *reinterpret_cast<const short8v*>(a0base + off);
                        a1 = *reinterpret_cast<const short8v*>(a1base + off);
                    } else {
                        int ks = kstep - 8;
                        if (ks < 3) {
                            int k0 = ks * 32 + kg * 8;
                            float4 l0 = *reinterpret_cast<const float4*>(loop_rel + k0);
                            float4 l1 = *reinterpret_cast<const float4*>(loop_rel + k0 + 4);
                            float4 lo0 = *reinterpret_cast<const float4*>(Arow0 + k0);
                            float4 hi0 = *reinterpret_cast<const float4*>(Arow0 + k0 + 4);
                            float4 lo1 = *reinterpret_cast<const float4*>(Arow1 + k0);
                            float4 hi1 = *reinterpret_cast<const float4*>(Arow1 + k0 + 4);
                            a0[0]=f2bf(lo0.x*l0.x); a0[1]=f2bf(lo0.y*l0.y); a0[2]=f2bf(lo0.z*l0.z); a0[3]=f2bf(lo0.w*l0.w);
                            a0[4]=f2bf(hi0.x*l1.x); a0[5]=f2bf(hi0.y*l1.y); a0[6]=f2bf(hi0.z*l1.z); a0[7]=f2bf(hi0.w*l1.w);
                            a1[0]=f2bf(lo1.x*l0.x); a1[1]=f2bf(lo1.y*l0.y); a1[2]=f2bf(lo1.z*l0.z); a1[3]=f2bf(lo1.w*l0.w);
                            a1[4]=f2bf(hi1.x*l1.x); a1[5]=f2bf(hi1.y*l1.y); a1[6]=f2bf(hi1.z*l1.z); a1[7]=f2bf(hi1.w*l1.w);
                        } else if (kg == 0) {
                            float4 l0 = *reinterpret_cast<const float4*>(loop_rel + 96);
                            float4 lo0 = *reinterpret_cast<const float4*>(Arow0 + 96);
                            float4 lo1 = *reinterpret_cast<const float4*>(Arow1 + 96);
                            a0[0]=f2bf(lo0.x*l0.x); a0[1]=f2bf(lo0.y*l0.y); a0[2]=f2bf(lo0.z*l0.z); a0[3]=f2bf(lo0.w*l0.w);
                            a1[0]=f2bf(lo1.x*l0.x); a1[1]=f2bf(lo1.y*l0.y); a1[2]=f2bf(lo1.z*l0.z); a1[3]=f2bf(lo1.w*l0.w);
                        }
                    }
                    afr0[kk] = a0; afr1[kk] = a1;
                }
            }
        }
        // ---- stage this half's W fragments into LDS (overlaps A loads) ----
        for (int i = tid; i < HALF_FRAGS; i += 512)
            wlds[i] = wfragv[h * HALF_FRAGS + i];
        __syncthreads();
        if (t0v) {
#pragma unroll
            for (int kk = 0; kk < 6; ++kk) {
#pragma unroll
                for (int nt = 0; nt < 7; ++nt) {
                    short8v bf = wlds[(kk * 7 + nt) * 64 + lane];
                    acc0[nt] = __builtin_amdgcn_mfma_f32_16x16x32_bf16(afr0[kk], bf, acc0[nt], 0, 0, 0);
                    acc1[nt] = __builtin_amdgcn_mfma_f32_16x16x32_bf16(afr1[kk], bf, acc1[nt], 0, 0, 0);
                }
            }
        }
    }

    // ---- epilogue: store + fused column stats ----
    if (t0v) {
#pragma unroll
        for (int nt = 0; nt < 7; ++nt) {
            int col = nt * 16 + cbase;
            if (col < DIM) {
                float ps = 0.f, pq = 0.f;
#pragma unroll
                for (int r = 0; r < 4; ++r) {
                    int orow = pair * 32 + kg * 4 + r;
                    if (orow < NE) {
                        float v = acc0[nt][r];
                        out[(size_t)orow * DIM + col] = v;
                        ps += v; pq += v * v;
                    }
                }
#pragma unroll
                for (int r = 0; r < 4; ++r) {
                    int orow = pair * 32 + 16 + kg * 4 + r;
                    if (orow < NE) {
                        float v = acc1[nt][r];
                        out[(size_t)orow * DIM + col] = v;
                        ps += v; pq += v * v;
                    }
                }
                atomicAdd(&cs[col], ps);
                atomicAdd(&cq[col], pq);
            }
        }
    }
    __syncthreads();
    if (tid < DIM) {
        atomicAdd(&colsum[tid], cs[tid]);
        atomicAdd(&colsumsq[tid], cq[tid]);
    }
}

// ============ BN + tanh with inline finalize ============
__global__ void k_bn_tanh4(float* __restrict__ v, const float* __restrict__ colsum,
                           const float* __restrict__ colsumsq,
                           const float* __restrict__ gamma, const float* __restrict__ beta,
                           float invN, int total4) {
    int i = blockIdx.x * blockDim.x + threadIdx.x;
    if (i >= total4) return;
    int d = (i % 25) * 4;
    float4 val = reinterpret_cast<float4*>(v)[i];
    float4 sm = *reinterpret_cast<const float4*>(colsum + d);
    float4 sq = *reinterpret_cast<const float4*>(colsumsq + d);
    float4 g  = *reinterpret_cast<const float4*>(gamma + d);
    float4 b  = *reinterpret_cast<const float4*>(beta + d);
#define BNT(c) { float mu = sm.c * invN; float var = sq.c * invN - mu * mu;            \
                 if (var < 0.f) var = 0.f;                                             \
                 float s = rsqrtf(var * (1.0f / 9.0f) + BN_EPS) * (1.0f / 3.0f) * g.c; \
                 float t = b.c - mu * s;                                               \
                 val.c = tanhf(val.c * s + t); }
    BNT(x) BNT(y) BNT(z) BNT(w)
#undef BNT
    reinterpret_cast<float4*>(v)[i] = val;
}

extern "C" void kernel_launch(void* const* d_in, const int* in_sizes, int n_in,
                              void* d_out, int out_size, void* d_ws, size_t ws_size,
                              hipStream_t stream) {
    const float* x        = (const float*)d_in[0];
    const int*   ei       = (const int*)d_in[1];
    const int*   et       = (const int*)d_in[2];
    const float* rel      = (const float*)d_in[3];
    const float* w_in     = (const float*)d_in[4];
    const float* w_out    = (const float*)d_in[5];
    const float* w_loop   = (const float*)d_in[6];
    const float* w_rel    = (const float*)d_in[7];
    const float* loop_rel = (const float*)d_in[8];
    const float* gamma    = (const float*)d_in[10];
    const float* beta     = (const float*)d_in[11];

    const int NE = in_sizes[0] / DIM;     // 50000
    const int E  = in_sizes[2] / 2;       // 500000

    float* out  = (float*)d_out;
    float* out2 = out + (size_t)NE * DIM;
    const int relRows = in_sizes[3] / DIM;

    const int B = 256;
    const size_t twoNE = 2 * (size_t)NE;
    const int n = (int)twoNE;
    const int nb = (n + 1023) / 1024;
    const int WFRAG_SHORTS = 3 * 4 * 7 * 64 * 8;
    const int WFRAG_INTS = WFRAG_SHORTS / 2;

    // ws layout (ints):
    // hist[2NE] | colsum[128] colsumsq[128] | blocksum[128]
    // | dinv[2NE] | base[2NE+16] | cursor[2NE] | wfrag[21504] | packed[2E] | abuf[(2|3)NE*64]
    int* wsI = (int*)d_ws;
    int*   hist     = wsI;
    float* colsum   = (float*)(hist + twoNE);
    float* colsumsq = colsum + 128;
    int*   blocksum = (int*)(colsumsq + 128);
    float* dinv     = (float*)(blocksum + 128);
    int*   base     = (int*)(dinv + twoNE);
    int*   cursor   = base + twoNE + 16;
    short* wfrag    = (short*)(cursor + twoNE);
    unsigned int* packed = (unsigned int*)(cursor + twoNE + WFRAG_INTS);
    short* abuf     = (short*)(packed + 2 * (size_t)E);

    const size_t fixedInts = twoNE + 256 + 128 + twoNE + (twoNE + 16) + twoNE
                             + WFRAG_INTS + 2 * (size_t)E;
    const size_t needXL = (fixedInts + 3 * (size_t)NE * (AGG_STRIDE / 2)) * 4;
    const int hasXL = (ws_size >= needXL) ? 1 : 0;
    short* xl = hasXL ? (abuf + twoNE * AGG_STRIDE) : nullptr;

    const int relTotal4 = relRows * (DIM / 4);
    const int nbW = (WPREP_THREADS + 255) / 256;
    const int nbR = (relTotal4 + 255) / 256;
    const int nbX = hasXL ? ((NE * 25 + 255) / 256) : 0;

    hipMemsetAsync(hist, 0, (twoNE + 256) * 4, stream);

    k_hist<<<1024, B, 0, stream>>>(ei, hist, E, NE);
    k_scanA<<<nb, B, 0, stream>>>(hist, base, blocksum, dinv, n);
    k_scanC<<<nb, B, 0, stream>>>(base, cursor, blocksum, n, 2 * E, nb);
    k_scatwrel<<<SC_BLOCKS + nbW + nbR + nbX, B, 0, stream>>>(
        ei, et, cursor, packed, E, NE, w_in, w_out, w_loop, wfrag,
        rel, w_rel, out2, nbW, relTotal4, x, loop_rel, xl, nbR);
    k_agg2<<<(n + 3) / 4, B, 0, stream>>>(packed, base, x, rel, dinv, abuf, NE);

    int nPairs = (NE + 31) / 32;
    k_gemm_mfma<<<(nPairs + 7) / 8, 512, 0, stream>>>(abuf, x, loop_rel, hasXL, wfrag,
                                                      out, colsum, colsumsq, NE);

    int total4 = NE * (DIM / 4);
    k_bn_tanh4<<<(total4 + B - 1) / B, B, 0, stream>>>(out, colsum, colsumsq,
                                                       gamma, beta, 1.0f / NE, total4);
}

// Round 12
// 203.025 us; speedup vs baseline: 1.2258x; 1.0892x over previous
//
#include <hip/hip_runtime.h>
#include <hip/hip_bf16.h>
#include <math.h>

#define DIM 100
#define BN_EPS 1e-5f
#define AGG_STRIDE 128   // shorts per agg row (100 valid + 28 zero pad) -> 256B
#define SC_BLOCKS 1024
#define HALF_FRAGS (6 * 7 * 64)   // 2688 fragments of 16B = 43008 B per half

using short8v = __attribute__((ext_vector_type(8))) short;
using f32x4v  = __attribute__((ext_vector_type(4))) float;

__device__ __forceinline__ short f2bf(float f) {
    unsigned u = __float_as_uint(f);
    unsigned r = (u + 0x7fffu + ((u >> 16) & 1u)) >> 16;
    return (short)r;
}

// ============ phase 1a: histogram + rank capture (ONE atomic pass) ============
__global__ void k_histrank(const int* __restrict__ ei, int* __restrict__ hist,
                           unsigned short* __restrict__ rank, int E, int NE) {
    int twoE = 2 * E;
    int n4 = twoE >> 2;
    int i4 = blockIdx.x * blockDim.x + threadIdx.x;
    int stride = gridDim.x * blockDim.x;
    for (; i4 < n4; i4 += stride) {
        int4 v = reinterpret_cast<const int4*>(ei)[i4];
        int b = i4 * 4;
        int r0 = atomicAdd(&hist[((b + 0 < E) ? 0 : NE) + v.x], 1);
        int r1 = atomicAdd(&hist[((b + 1 < E) ? 0 : NE) + v.y], 1);
        int r2 = atomicAdd(&hist[((b + 2 < E) ? 0 : NE) + v.z], 1);
        int r3 = atomicAdd(&hist[((b + 3 < E) ? 0 : NE) + v.w], 1);
        ushort4 rr;
        rr.x = (unsigned short)r0; rr.y = (unsigned short)r1;
        rr.z = (unsigned short)r2; rr.w = (unsigned short)r3;
        reinterpret_cast<ushort4*>(rank)[i4] = rr;
    }
    if (blockIdx.x == 0 && threadIdx.x == 0) {
        for (int i = n4 * 4; i < twoE; ++i)
            rank[i] = (unsigned short)atomicAdd(&hist[((i < E) ? 0 : NE) + ei[i]], 1);
    }
}

// ============ phase 1b: plain histogram (fallback when no rank buffer) ============
__global__ void k_hist(const int* __restrict__ ei, int* __restrict__ hist, int E, int NE) {
    int twoE = 2 * E;
    int n4 = twoE >> 2;
    int i4 = blockIdx.x * blockDim.x + threadIdx.x;
    int stride = gridDim.x * blockDim.x;
    for (; i4 < n4; i4 += stride) {
        int4 v = reinterpret_cast<const int4*>(ei)[i4];
        int b = i4 * 4;
        atomicAdd(&hist[((b + 0 < E) ? 0 : NE) + v.x], 1);
        atomicAdd(&hist[((b + 1 < E) ? 0 : NE) + v.y], 1);
        atomicAdd(&hist[((b + 2 < E) ? 0 : NE) + v.z], 1);
        atomicAdd(&hist[((b + 3 < E) ? 0 : NE) + v.w], 1);
    }
    if (blockIdx.x == 0 && threadIdx.x == 0) {
        for (int i = n4 * 4; i < twoE; ++i)
            atomicAdd(&hist[((i < E) ? 0 : NE) + ei[i]], 1);
    }
}

// ============ phase 2a: block-local exclusive scan (+ dinv fused) ============
__global__ void k_scanA(const int* __restrict__ hist, int* __restrict__ base,
                        int* __restrict__ blocksum, float* __restrict__ dinv, int n) {
    __shared__ int lsum[256];
    int tid = threadIdx.x;
    int i0 = blockIdx.x * 1024 + tid * 4;
    int v0 = (i0 + 0 < n) ? hist[i0 + 0] : 0;
    int v1 = (i0 + 1 < n) ? hist[i0 + 1] : 0;
    int v2 = (i0 + 2 < n) ? hist[i0 + 2] : 0;
    int v3 = (i0 + 3 < n) ? hist[i0 + 3] : 0;
    if (i0 + 0 < n) dinv[i0 + 0] = v0 > 0 ? rsqrtf((float)v0) : 0.f;
    if (i0 + 1 < n) dinv[i0 + 1] = v1 > 0 ? rsqrtf((float)v1) : 0.f;
    if (i0 + 2 < n) dinv[i0 + 2] = v2 > 0 ? rsqrtf((float)v2) : 0.f;
    if (i0 + 3 < n) dinv[i0 + 3] = v3 > 0 ? rsqrtf((float)v3) : 0.f;
    int s = v0 + v1 + v2 + v3;
    lsum[tid] = s;
    __syncthreads();
    for (int off = 1; off < 256; off <<= 1) {
        int t = (tid >= off) ? lsum[tid - off] : 0;
        __syncthreads();
        lsum[tid] += t;
        __syncthreads();
    }
    int excl = lsum[tid] - s;
    if (i0 + 0 < n) base[i0 + 0] = excl;
    if (i0 + 1 < n) base[i0 + 1] = excl + v0;
    if (i0 + 2 < n) base[i0 + 2] = excl + v0 + v1;
    if (i0 + 3 < n) base[i0 + 3] = excl + v0 + v1 + v2;
    if (tid == 255) blocksum[blockIdx.x] = lsum[255];
}

// ============ phase 2b: apply block offsets (cursor written only if given) ============
__global__ void k_scanC(int* __restrict__ base, int* cursor,
                        const int* __restrict__ blocksum, int n, int total, int nb) {
    __shared__ int s[256];
    int tid = threadIdx.x;
    int v = (tid < nb) ? blocksum[tid] : 0;
    s[tid] = v;
    __syncthreads();
    for (int off = 1; off < 256; off <<= 1) {
        int t = (tid >= off) ? s[tid - off] : 0;
        __syncthreads();
        s[tid] += t;
        __syncthreads();
    }
    int boff = (blockIdx.x > 0) ? s[blockIdx.x - 1] : 0;
    int i0 = blockIdx.x * 1024 + tid * 4;
#pragma unroll
    for (int j = 0; j < 4; ++j) {
        int i = i0 + j;
        if (i < n) {
            int w = base[i] + boff;
            base[i] = w;
            if (cursor) cursor[i] = w;
        }
    }
    if (blockIdx.x == 0 && tid == 0) base[n] = total;
}

// ============ phase 3: scatter (atomic-free if rank) + W frag prep + rel mm + xl prep ========
#define WPREP_THREADS (3 * 4 * 7 * 64)
__global__ void k_scatwrel(const int* __restrict__ ei, const int* __restrict__ et,
                           const int* __restrict__ base, int* cursor,
                           const unsigned short* rank,
                           unsigned int* __restrict__ packed, int E, int NE,
                           const float* __restrict__ w_in, const float* __restrict__ w_out,
                           const float* __restrict__ w_loop, short* __restrict__ wfrag,
                           const float* __restrict__ rel, const float* __restrict__ w_rel,
                           float* __restrict__ out2, int nbW, int relTotal4,
                           const float* __restrict__ x, const float* __restrict__ loop_rel,
                           short* __restrict__ xl, int nbR) {
    int tid = threadIdx.x;
    int b = (int)blockIdx.x;
    if (b < SC_BLOCKS) {
        int twoE = 2 * E;
        int n4 = twoE >> 2;
        int i4 = b * 256 + tid;
        int stride = SC_BLOCKS * 256;
        if (rank) {
            // atomic-free scatter: pos = base[slot] + rank
            for (; i4 < n4; i4 += stride) {
                int4 r4 = reinterpret_cast<const int4*>(ei)[i4];
                int4 c4 = *reinterpret_cast<const int4*>(ei + twoE + i4 * 4);
                int4 t4 = reinterpret_cast<const int4*>(et)[i4];
                ushort4 k4 = reinterpret_cast<const ushort4*>(rank)[i4];
                int bidx = i4 * 4;
                int b0 = base[((bidx + 0 < E) ? 0 : NE) + r4.x];
                int b1 = base[((bidx + 1 < E) ? 0 : NE) + r4.y];
                int b2 = base[((bidx + 2 < E) ? 0 : NE) + r4.z];
                int b3 = base[((bidx + 3 < E) ? 0 : NE) + r4.w];
                __builtin_nontemporal_store(
                    (unsigned int)c4.x | ((unsigned int)t4.x << 17), &packed[b0 + k4.x]);
                __builtin_nontemporal_store(
                    (unsigned int)c4.y | ((unsigned int)t4.y << 17), &packed[b1 + k4.y]);
                __builtin_nontemporal_store(
                    (unsigned int)c4.z | ((unsigned int)t4.z << 17), &packed[b2 + k4.z]);
                __builtin_nontemporal_store(
                    (unsigned int)c4.w | ((unsigned int)t4.w << 17), &packed[b3 + k4.w]);
            }
            if (b == 0 && tid == 0) {
                for (int i = n4 * 4; i < twoE; ++i) {
                    int pos = base[((i < E) ? 0 : NE) + ei[i]] + rank[i];
                    packed[pos] = (unsigned int)ei[twoE + i] | ((unsigned int)et[i] << 17);
                }
            }
        } else {
            // fallback: cursor atomics
            for (; i4 < n4; i4 += stride) {
                int4 r4 = reinterpret_cast<const int4*>(ei)[i4];
                int4 c4 = *reinterpret_cast<const int4*>(ei + twoE + i4 * 4);
                int4 t4 = reinterpret_cast<const int4*>(et)[i4];
                int bidx = i4 * 4;
#define SCAT(comp, o) { int slot = ((bidx + o < E) ? 0 : NE) + r4.comp;                  \
                        int pos = atomicAdd(&cursor[slot], 1);                           \
                        packed[pos] = (unsigned int)c4.comp | ((unsigned int)t4.comp << 17); }
                SCAT(x, 0) SCAT(y, 1) SCAT(z, 2) SCAT(w, 3)
#undef SCAT
            }
            if (b == 0 && tid == 0) {
                for (int i = n4 * 4; i < twoE; ++i) {
                    int slot = ((i < E) ? 0 : NE) + ei[i];
                    int pos = atomicAdd(&cursor[slot], 1);
                    packed[pos] = (unsigned int)ei[twoE + i] | ((unsigned int)et[i] << 17);
                }
            }
        }
    } else if (b < SC_BLOCKS + nbW) {
        int g = (b - SC_BLOCKS) * 256 + tid;
        if (g >= WPREP_THREADS) return;
        int lane = g & 63;
        int rest = g >> 6;
        int nt = rest % 7;
        int ks = (rest / 7) % 4;
        int src = rest / 28;
        const float* W = (src == 0) ? w_in : (src == 1) ? w_out : w_loop;
        int col = nt * 16 + (lane & 15);
        short8v frag;
#pragma unroll
        for (int j = 0; j < 8; ++j) {
            int k = ks * 32 + ((lane >> 4) << 3) + j;
            float v = (k < DIM && col < DIM) ? W[k * DIM + col] : 0.f;
            frag[j] = f2bf(v);
        }
        reinterpret_cast<short8v*>(wfrag)[g] = frag;
    } else if (b < SC_BLOCKS + nbW + nbR) {
        int i = (b - SC_BLOCKS - nbW) * 256 + tid;
        if (i >= relTotal4) return;
        int r = i / 25;
        int d = (i - r * 25) * 4;
        const float* a = rel + r * DIM;
        float4 acc = make_float4(0.f, 0.f, 0.f, 0.f);
#pragma unroll 4
        for (int k = 0; k < DIM; ++k) {
            float av = a[k];
            float4 w = *reinterpret_cast<const float4*>(w_rel + k * DIM + d);
            acc.x += av * w.x; acc.y += av * w.y; acc.z += av * w.z; acc.w += av * w.w;
        }
        *reinterpret_cast<float4*>(out2 + r * DIM + d) = acc;
    } else {
        if (!xl) return;
        int i = (b - SC_BLOCKS - nbW - nbR) * 256 + tid;
        if (i >= NE * 25) return;
        int r = i / 25;
        int c4 = (i - r * 25) * 4;
        float4 xv = *reinterpret_cast<const float4*>(x + (size_t)r * DIM + c4);
        float4 lv = *reinterpret_cast<const float4*>(loop_rel + c4);
        short4 sv;
        sv.x = f2bf(xv.x * lv.x); sv.y = f2bf(xv.y * lv.y);
        sv.z = f2bf(xv.z * lv.z); sv.w = f2bf(xv.w * lv.w);
        short* dst = xl + (size_t)r * AGG_STRIDE;
        *reinterpret_cast<short4*>(dst + c4) = sv;
        if (c4 == 96) {
            short4 z; z.x = 0; z.y = 0; z.z = 0; z.w = 0;
#pragma unroll
            for (int p = 100; p < 128; p += 4)
                *reinterpret_cast<short4*>(dst + p) = z;
        }
    }
}

// ============ phase 4: gather-aggregate, one CSR row per wave, 6 edges in flight ===========
__global__ __launch_bounds__(256) void k_agg2(
    const unsigned int* __restrict__ packed, const int* __restrict__ base,
    const float* __restrict__ x, const float* __restrict__ rel,
    const float* __restrict__ dinv,
    short* __restrict__ aggbf, int NE) {
    int tid = threadIdx.x;
    int row = blockIdx.x * 4 + (tid >> 6);
    if (row >= 2 * NE) return;
    int lane = tid & 63;
    int sub = lane >> 5;
    int slot = lane & 31;
    int d = (slot < 25) ? slot * 4 : 96;
    int dbase = (row < NE) ? 0 : NE;
    float dr = dinv[row];
    int s = base[row], e = base[row + 1];

    float4 acc0 = make_float4(0.f, 0.f, 0.f, 0.f);
    float4 acc1 = make_float4(0.f, 0.f, 0.f, 0.f);
    float4 acc2 = make_float4(0.f, 0.f, 0.f, 0.f);
    int j = s + sub;
    for (; j + 4 < e; j += 6) {
        unsigned int p0 = packed[j];
        unsigned int p1 = packed[j + 2];
        unsigned int p2 = packed[j + 4];
        int c0 = (int)(p0 & 0x1FFFFu), t0 = (int)(p0 >> 17);
        int c1 = (int)(p1 & 0x1FFFFu), t1 = (int)(p1 >> 17);
        int c2 = (int)(p2 & 0x1FFFFu), t2 = (int)(p2 >> 17);
        float n0 = dr * dinv[dbase + c0];
        float n1 = dr * dinv[dbase + c1];
        float n2 = dr * dinv[dbase + c2];
        float4 xv0 = *reinterpret_cast<const float4*>(x + c0 * DIM + d);
        float4 rv0 = *reinterpret_cast<const float4*>(rel + t0 * DIM + d);
        float4 xv1 = *reinterpret_cast<const float4*>(x + c1 * DIM + d);
        float4 rv1 = *reinterpret_cast<const float4*>(rel + t1 * DIM + d);
        float4 xv2 = *reinterpret_cast<const float4*>(x + c2 * DIM + d);
        float4 rv2 = *reinterpret_cast<const float4*>(rel + t2 * DIM + d);
        acc0.x += xv0.x * rv0.x * n0; acc0.y += xv0.y * rv0.y * n0;
        acc0.z += xv0.z * rv0.z * n0; acc0.w += xv0.w * rv0.w * n0;
        acc1.x += xv1.x * rv1.x * n1; acc1.y += xv1.y * rv1.y * n1;
        acc1.z += xv1.z * rv1.z * n1; acc1.w += xv1.w * rv1.w * n1;
        acc2.x += xv2.x * rv2.x * n2; acc2.y += xv2.y * rv2.y * n2;
        acc2.z += xv2.z * rv2.z * n2; acc2.w += xv2.w * rv2.w * n2;
    }
    for (; j < e; j += 2) {
        unsigned int p0 = packed[j];
        int c0 = (int)(p0 & 0x1FFFFu), t0 = (int)(p0 >> 17);
        float n0 = dr * dinv[dbase + c0];
        float4 xv0 = *reinterpret_cast<const float4*>(x + c0 * DIM + d);
        float4 rv0 = *reinterpret_cast<const float4*>(rel + t0 * DIM + d);
        acc0.x += xv0.x * rv0.x * n0; acc0.y += xv0.y * rv0.y * n0;
        acc0.z += xv0.z * rv0.z * n0; acc0.w += xv0.w * rv0.w * n0;
    }
    acc0.x += acc1.x + acc2.x; acc0.y += acc1.y + acc2.y;
    acc0.z += acc1.z + acc2.z; acc0.w += acc1.w + acc2.w;
    acc0.x += __shfl_down(acc0.x, 32, 64);
    acc0.y += __shfl_down(acc0.y, 32, 64);
    acc0.z += __shfl_down(acc0.z, 32, 64);
    acc0.w += __shfl_down(acc0.w, 32, 64);
    if (sub == 0) {
        short4 sv;
        if (slot < 25) {
            sv.x = f2bf(acc0.x); sv.y = f2bf(acc0.y);
            sv.z = f2bf(acc0.z); sv.w = f2bf(acc0.w);
        } else {
            sv.x = 0; sv.y = 0; sv.z = 0; sv.w = 0;
        }
        *reinterpret_cast<short4*>(aggbf + (size_t)row * AGG_STRIDE + slot * 4) = sv;
    }
}

// ============ MFMA GEMM: 8 waves/block, 2 row-tiles/wave, A-frags register-prefetched ============
__global__ __launch_bounds__(512) void k_gemm_mfma(
    const short* __restrict__ abuf,
    const float* __restrict__ x, const float* __restrict__ loop_rel, int hasXL,
    const short* __restrict__ wfrag, float* __restrict__ out,
    float* __restrict__ colsum, float* __restrict__ colsumsq, int NE) {
    __shared__ short8v wlds[HALF_FRAGS];
    __shared__ float cs[112], cq[112];
    int tid = threadIdx.x;
    if (tid < 112) { cs[tid] = 0.f; cq[tid] = 0.f; }

    int wv = tid >> 6;
    int lane = tid & 63;
    int kg = lane >> 4;
    int cbase = lane & 15;
    int pair = blockIdx.x * 8 + wv;
    bool t0v = (pair * 32 < NE);
    int r0 = pair * 32 + cbase;
    int r1 = r0 + 16;
    int rA0 = (r0 < NE) ? r0 : (NE - 1);
    int rA1 = (r1 < NE) ? r1 : (NE - 1);
    const float* Arow0 = x + (size_t)rA0 * DIM;
    const float* Arow1 = x + (size_t)rA1 * DIM;
    const short8v* wfragv = reinterpret_cast<const short8v*>(wfrag);
    const short* a0base = abuf + (size_t)rA0 * AGG_STRIDE + kg * 8;
    const short* a1base = abuf + (size_t)rA1 * AGG_STRIDE + kg * 8;
    const size_t srcOff = (size_t)NE * AGG_STRIDE;

    f32x4v acc0[7], acc1[7];
#pragma unroll
    for (int nt = 0; nt < 7; ++nt) {
        acc0[nt] = (f32x4v){0.f, 0.f, 0.f, 0.f};
        acc1[nt] = (f32x4v){0.f, 0.f, 0.f, 0.f};
    }

#pragma unroll
    for (int h = 0; h < 2; ++h) {
        if (h > 0) __syncthreads();
        short8v afr0[6], afr1[6];
        if (t0v) {
            if (hasXL) {
#pragma unroll
                for (int kk = 0; kk < 6; ++kk) {
                    int kstep = h * 6 + kk;
                    size_t off = (size_t)(kstep >> 2) * srcOff + (kstep & 3) * 32;
                    afr0[kk] = *reinterpret_cast<const short8v*>(a0base + off);
                    afr1[kk] = *reinterpret_cast<const short8v*>(a1base + off);
                }
            } else {
#pragma unroll
                for (int kk = 0; kk < 6; ++kk) {
                    int kstep = h * 6 + kk;
                    short8v a0 = (short8v){0,0,0,0,0,0,0,0};
                    short8v a1 = (short8v){0,0,0,0,0,0,0,0};
                    if (kstep < 8) {
                        size_t off = (size_t)(kstep >> 2) * srcOff + (kstep & 3) * 32;
                        a0 = *reinterpret_cast<const short8v*>(a0base + off);
                        a1 = *reinterpret_cast<const short8v*>(a1base + off);
                    } else {
                        int ks = kstep - 8;
                        if (ks < 3) {
                            int k0 = ks * 32 + kg * 8;
                            float4 l0 = *reinterpret_cast<const float4*>(loop_rel + k0);
                            float4 l1 = *reinterpret_cast<const float4*>(loop_rel + k0 + 4);
                            float4 lo0 = *reinterpret_cast<const float4*>(Arow0 + k0);
                            float4 hi0 = *reinterpret_cast<const float4*>(Arow0 + k0 + 4);
                            float4 lo1 = *reinterpret_cast<const float4*>(Arow1 + k0);
                            float4 hi1 = *reinterpret_cast<const float4*>(Arow1 + k0 + 4);
                            a0[0]=f2bf(lo0.x*l0.x); a0[1]=f2bf(lo0.y*l0.y); a0[2]=f2bf(lo0.z*l0.z); a0[3]=f2bf(lo0.w*l0.w);
                            a0[4]=f2bf(hi0.x*l1.x); a0[5]=f2bf(hi0.y*l1.y); a0[6]=f2bf(hi0.z*l1.z); a0[7]=f2bf(hi0.w*l1.w);
                            a1[0]=f2bf(lo1.x*l0.x); a1[1]=f2bf(lo1.y*l0.y); a1[2]=f2bf(lo1.z*l0.z); a1[3]=f2bf(lo1.w*l0.w);
                            a1[4]=f2bf(hi1.x*l1.x); a1[5]=f2bf(hi1.y*l1.y); a1[6]=f2bf(hi1.z*l1.z); a1[7]=f2bf(hi1.w*l1.w);
                        } else if (kg == 0) {
                            float4 l0 = *reinterpret_cast<const float4*>(loop_rel + 96);
                            float4 lo0 = *reinterpret_cast<const float4*>(Arow0 + 96);
                            float4 lo1 = *reinterpret_cast<const float4*>(Arow1 + 96);
                            a0[0]=f2bf(lo0.x*l0.x); a0[1]=f2bf(lo0.y*l0.y); a0[2]=f2bf(lo0.z*l0.z); a0[3]=f2bf(lo0.w*l0.w);
                            a1[0]=f2bf(lo1.x*l0.x); a1[1]=f2bf(lo1.y*l0.y); a1[2]=f2bf(lo1.z*l0.z); a1[3]=f2bf(lo1.w*l0.w);
                        }
                    }
                    afr0[kk] = a0; afr1[kk] = a1;
                }
            }
        }
        for (int i = tid; i < HALF_FRAGS; i += 512)
            wlds[i] = wfragv[h * HALF_FRAGS + i];
        __syncthreads();
        if (t0v) {
#pragma unroll
            for (int kk = 0; kk < 6; ++kk) {
#pragma unroll
                for (int nt = 0; nt < 7; ++nt) {
                    short8v bf = wlds[(kk * 7 + nt) * 64 + lane];
                    acc0[nt] = __builtin_amdgcn_mfma_f32_16x16x32_bf16(afr0[kk], bf, acc0[nt], 0, 0, 0);
                    acc1[nt] = __builtin_amdgcn_mfma_f32_16x16x32_bf16(afr1[kk], bf, acc1[nt], 0, 0, 0);
                }
            }
        }
    }

    if (t0v) {
#pragma unroll
        for (int nt = 0; nt < 7; ++nt) {
            int col = nt * 16 + cbase;
            if (col < DIM) {
                float ps = 0.f, pq = 0.f;
#pragma unroll
                for (int r = 0; r < 4; ++r) {
                    int orow = pair * 32 + kg * 4 + r;
                    if (orow < NE) {
                        float v = acc0[nt][r];
                        out[(size_t)orow * DIM + col] = v;
                        ps += v; pq += v * v;
                    }
                }
#pragma unroll
                for (int r = 0; r < 4; ++r) {
                    int orow = pair * 32 + 16 + kg * 4 + r;
                    if (orow < NE) {
                        float v = acc1[nt][r];
                        out[(size_t)orow * DIM + col] = v;
                        ps += v; pq += v * v;
                    }
                }
                atomicAdd(&cs[col], ps);
                atomicAdd(&cq[col], pq);
            }
        }
    }
    __syncthreads();
    if (tid < DIM) {
        atomicAdd(&colsum[tid], cs[tid]);
        atomicAdd(&colsumsq[tid], cq[tid]);
    }
}

// ============ BN + tanh with inline finalize ============
__global__ void k_bn_tanh4(float* __restrict__ v, const float* __restrict__ colsum,
                           const float* __restrict__ colsumsq,
                           const float* __restrict__ gamma, const float* __restrict__ beta,
                           float invN, int total4) {
    int i = blockIdx.x * blockDim.x + threadIdx.x;
    if (i >= total4) return;
    int d = (i % 25) * 4;
    float4 val = reinterpret_cast<float4*>(v)[i];
    float4 sm = *reinterpret_cast<const float4*>(colsum + d);
    float4 sq = *reinterpret_cast<const float4*>(colsumsq + d);
    float4 g  = *reinterpret_cast<const float4*>(gamma + d);
    float4 b  = *reinterpret_cast<const float4*>(beta + d);
#define BNT(c) { float mu = sm.c * invN; float var = sq.c * invN - mu * mu;            \
                 if (var < 0.f) var = 0.f;                                             \
                 float s = rsqrtf(var * (1.0f / 9.0f) + BN_EPS) * (1.0f / 3.0f) * g.c; \
                 float t = b.c - mu * s;                                               \
                 val.c = tanhf(val.c * s + t); }
    BNT(x) BNT(y) BNT(z) BNT(w)
#undef BNT
    reinterpret_cast<float4*>(v)[i] = val;
}

extern "C" void kernel_launch(void* const* d_in, const int* in_sizes, int n_in,
                              void* d_out, int out_size, void* d_ws, size_t ws_size,
                              hipStream_t stream) {
    const float* x        = (const float*)d_in[0];
    const int*   ei       = (const int*)d_in[1];
    const int*   et       = (const int*)d_in[2];
    const float* rel      = (const float*)d_in[3];
    const float* w_in     = (const float*)d_in[4];
    const float* w_out    = (const float*)d_in[5];
    const float* w_loop   = (const float*)d_in[6];
    const float* w_rel    = (const float*)d_in[7];
    const float* loop_rel = (const float*)d_in[8];
    const float* gamma    = (const float*)d_in[10];
    const float* beta     = (const float*)d_in[11];

    const int NE = in_sizes[0] / DIM;     // 50000
    const int E  = in_sizes[2] / 2;       // 500000

    float* out  = (float*)d_out;
    float* out2 = out + (size_t)NE * DIM;
    const int relRows = in_sizes[3] / DIM;

    const int B = 256;
    const size_t twoNE = 2 * (size_t)NE;
    const int n = (int)twoNE;
    const int nb = (n + 1023) / 1024;
    const int WFRAG_SHORTS = 3 * 4 * 7 * 64 * 8;
    const int WFRAG_INTS = WFRAG_SHORTS / 2;

    // ws layout (ints):
    // hist[2NE] | colsum[128] colsumsq[128] | blocksum[128]
    // | dinv[2NE] | base[2NE+16] | cursor[2NE] | wfrag | packed[2E] | rank[E ints]? | abuf | xl?
    int* wsI = (int*)d_ws;
    int*   hist     = wsI;
    float* colsum   = (float*)(hist + twoNE);
    float* colsumsq = colsum + 128;
    int*   blocksum = (int*)(colsumsq + 128);
    float* dinv     = (float*)(blocksum + 128);
    int*   base     = (int*)(dinv + twoNE);
    int*   cursor   = base + twoNE + 16;
    short* wfrag    = (short*)(cursor + twoNE);
    unsigned int* packed = (unsigned int*)(cursor + twoNE + WFRAG_INTS);

    const size_t fixedInts = twoNE + 256 + 128 + twoNE + (twoNE + 16) + twoNE
                             + WFRAG_INTS + 2 * (size_t)E;
    const size_t rankInts = ((size_t)E + 1) & ~1ull;   // 2E ushorts
    const size_t abuf2Ints = twoNE * (AGG_STRIDE / 2);
    const size_t xlInts = (size_t)NE * (AGG_STRIDE / 2);

    const int hasRank = (ws_size >= (fixedInts + rankInts + abuf2Ints) * 4) ? 1 : 0;
    const int hasXL = (ws_size >= (fixedInts + (hasRank ? rankInts : 0)
                                   + abuf2Ints + xlInts) * 4) ? 1 : 0;

    unsigned short* rank = hasRank ? (unsigned short*)(packed + 2 * (size_t)E) : nullptr;
    short* abuf = (short*)(packed + 2 * (size_t)E + (hasRank ? rankInts : 0));
    short* xl   = hasXL ? (abuf + twoNE * AGG_STRIDE) : nullptr;

    const int relTotal4 = relRows * (DIM / 4);
    const int nbW = (WPREP_THREADS + 255) / 256;
    const int nbR = (relTotal4 + 255) / 256;
    const int nbX = hasXL ? ((NE * 25 + 255) / 256) : 0;

    hipMemsetAsync(hist, 0, (twoNE + 256) * 4, stream);

    if (hasRank)
        k_histrank<<<1024, B, 0, stream>>>(ei, hist, rank, E, NE);
    else
        k_hist<<<1024, B, 0, stream>>>(ei, hist, E, NE);
    k_scanA<<<nb, B, 0, stream>>>(hist, base, blocksum, dinv, n);
    k_scanC<<<nb, B, 0, stream>>>(base, hasRank ? nullptr : cursor, blocksum, n, 2 * E, nb);
    k_scatwrel<<<SC_BLOCKS + nbW + nbR + nbX, B, 0, stream>>>(
        ei, et, base, cursor, rank, packed, E, NE, w_in, w_out, w_loop, wfrag,
        rel, w_rel, out2, nbW, relTotal4, x, loop_rel, xl, nbR);
    k_agg2<<<(n + 3) / 4, B, 0, stream>>>(packed, base, x, rel, dinv, abuf, NE);

    int nPairs = (NE + 31) / 32;
    k_gemm_mfma<<<(nPairs + 7) / 8, 512, 0, stream>>>(abuf, x, loop_rel, hasXL, wfrag,
                                                      out, colsum, colsumsq, NE);

    int total4 = NE * (DIM / 4);
    k_bn_tanh4<<<(total4 + B - 1) / B, B, 0, stream>>>(out, colsum, colsumsq,
                                                       gamma, beta, 1.0f / NE, total4);
}